// Round 3
// baseline (863.748 us; speedup 1.0000x reference)
//
#include <hip/hip_runtime.h>
#include <hip/hip_bf16.h>

#define THREADS 256
#define MTILE   32      // batch rows per block
#define HID     128
#define BATCH   32768
#define NFEAT   8

typedef __attribute__((ext_vector_type(4))) float f32x4;
typedef __attribute__((ext_vector_type(8))) short s16x8;

struct Ptrs {
    const float* feat[NFEAT];
    const float* wk[NFEAT];
    const float* wv[NFEAT];
    const float* q;
};

__device__ __forceinline__ unsigned short f2bf(float f) {
    union { __hip_bfloat16 h; unsigned short u; } c; c.h = __float2bfloat16(f); return c.u;
}

__device__ __forceinline__ s16x8 pack8(float4 x, float4 y) {
    s16x8 b;
    b[0] = (short)f2bf(x.x); b[1] = (short)f2bf(x.y);
    b[2] = (short)f2bf(x.z); b[3] = (short)f2bf(x.w);
    b[4] = (short)f2bf(y.x); b[5] = (short)f2bf(y.y);
    b[6] = (short)f2bf(y.z); b[7] = (short)f2bf(y.w);
    return b;
}

// runtime-indexed copies (prep kernel)
__device__ const int g_fdim[NFEAT] = {32, 64, 96, 128, 192, 256, 384, 512};
__device__ const int g_foff[NFEAT] = {0, 32, 96, 192, 320, 512, 768, 1152};
// compile-time copies (main-kernel templates derive D/FOFF from FI — can't mismatch)
constexpr int c_fdim[NFEAT] = {32, 64, 96, 128, 192, 256, 384, 512};
constexpr int c_foff[NFEAT] = {0, 32, 96, 192, 320, 512, 768, 1152};

// ---------------- fused prep: Wv -> bf16 B-fragment layout, and qk = (Wk^T q)/sqrt(128) ----------------
__global__ void prep_all(Ptrs p, unsigned short* WvB, float* qk) {
    int bid = blockIdx.x;
    if (bid < NFEAT * 8) {
        int fi    = bid >> 3;
        int slice = bid & 7;
        int D  = g_fdim[fi];
        int Dg = D >> 3;
        const float* Wv = p.wv[fi];
        unsigned short* out = WvB + 128 * g_foff[fi];
        int h0  = slice * 16;
        int cnt = 16 * Dg;
        for (int e = threadIdx.x; e < cnt; e += blockDim.x) {
            int h  = h0 + e / Dg;
            int kg = e - (e / Dg) * Dg;
            const float* src = Wv + h * D + kg * 8;
            float4 x = *reinterpret_cast<const float4*>(src);
            float4 y = *reinterpret_cast<const float4*>(src + 4);
            *reinterpret_cast<s16x8*>(out + (kg * 128 + h) * 8) = pack8(x, y);
        }
    } else {
        int i = bid - NFEAT * 8;
        int d = g_fdim[i];
        const float* Wk = p.wk[i];
        const float* q  = p.q;
        for (int c = threadIdx.x; c < d; c += blockDim.x) {
            float s = 0.f;
            #pragma unroll 8
            for (int h = 0; h < HID; ++h) s = fmaf(q[h], Wk[h * d + c], s);
            qk[g_foff[i] + c] = s * 0.08838834764831845f;   // 1/sqrt(128)
        }
    }
}

// ---------------- main kernel pieces (barrier-free: per-wave register streaming) ----------------

// A-fragment loads, straight from global in MFMA layout:
// lane (q4,l15) reads rows (l15, 16+l15), k = CK0 + kk*32 + q4*8 .. +8  (two float4)
template<int FI, int CK0, int DC>
__device__ __forceinline__ void loadA(const Ptrs& p, int row0, int l15, int q4, float4* fA) {
    constexpr int D  = c_fdim[FI];
    constexpr int KK = DC / 32;
    const float* b = p.feat[FI] + (size_t)(row0 + l15) * D + CK0 + q4 * 8;
    #pragma unroll
    for (int mt = 0; mt < 2; ++mt) {
        const float* bb = b + mt * 16 * D;
        #pragma unroll
        for (int kk = 0; kk < KK; ++kk) {
            fA[(mt * KK + kk) * 2 + 0] = *reinterpret_cast<const float4*>(bb + kk * 32);
            fA[(mt * KK + kk) * 2 + 1] = *reinterpret_cast<const float4*>(bb + kk * 32 + 4);
        }
    }
}

template<int FI, int CK0, int DC>
__device__ __forceinline__ void loadB(const unsigned short* WvB, int wave, int l15, int q4,
                                      s16x8 (&bf)[2][2]) {
    constexpr int FOFF = c_foff[FI];
    constexpr int KK = DC / 32;
    const unsigned short* Wb = WvB + 128 * FOFF;
    int hb = wave * 32 + l15;
    #pragma unroll
    for (int kk = 0; kk < KK; ++kk) {
        int kg = CK0 / 8 + kk * 4 + q4;
        bf[kk][0] = *reinterpret_cast<const s16x8*>(Wb + (kg * 128 + hb) * 8);
        bf[kk][1] = *reinterpret_cast<const s16x8*>(Wb + (kg * 128 + hb + 16) * 8);
    }
}

// score partial (fp32, before rounding) + convert staged fp32 -> bf16 fragments
template<int FI, int CK0, int DC, bool FIRST>
__device__ __forceinline__ void score_cvt(const float4* fA, const float* qkS, int q4,
                                          float (&spart)[2], s16x8 (&af)[2][2],
                                          f32x4 (&P)[2][2]) {
    constexpr int FOFF = c_foff[FI];
    constexpr int KK = DC / 32;
    if (FIRST) {
        spart[0] = spart[1] = 0.f;
        P[0][0] = P[0][1] = P[1][0] = P[1][1] = f32x4{0.f, 0.f, 0.f, 0.f};
    }
    #pragma unroll
    for (int kk = 0; kk < KK; ++kk) {
        float4 q0 = *reinterpret_cast<const float4*>(qkS + FOFF + CK0 + kk * 32 + q4 * 8);
        float4 q1 = *reinterpret_cast<const float4*>(qkS + FOFF + CK0 + kk * 32 + q4 * 8 + 4);
        #pragma unroll
        for (int mt = 0; mt < 2; ++mt) {
            float4 x = fA[(mt * KK + kk) * 2 + 0];
            float4 y = fA[(mt * KK + kk) * 2 + 1];
            spart[mt] += x.x * q0.x + x.y * q0.y + x.z * q0.z + x.w * q0.w
                       + y.x * q1.x + y.y * q1.y + y.z * q1.z + y.w * q1.w;
            af[mt][kk] = pack8(x, y);
        }
    }
}

template<int FI, int DC, bool LAST>
__device__ __forceinline__ void mfma_tail(const s16x8 (&af)[2][2], const s16x8 (&bf)[2][2],
                                          f32x4 (&P)[2][2], f32x4 (&O)[2][2],
                                          float (&spart)[2], float (&Zacc)[2],
                                          float* wAll, int tid, int lane, int l15, int q4) {
    constexpr int KK = DC / 32;
    #pragma unroll
    for (int kk = 0; kk < KK; ++kk) {
        #pragma unroll
        for (int mt = 0; mt < 2; ++mt) {
            P[mt][0] = __builtin_amdgcn_mfma_f32_16x16x32_bf16(af[mt][kk], bf[kk][0], P[mt][0], 0, 0, 0);
            P[mt][1] = __builtin_amdgcn_mfma_f32_16x16x32_bf16(af[mt][kk], bf[kk][1], P[mt][1], 0, 0, 0);
        }
    }
    if (LAST) {
        // lanes within a q4-group hold partial sums over their k-slice; combine the 4 groups.
        int sb = (lane & 48);              // own 16-lane group base
        int wb = sb + q4 * 4;              // src lanes holding rows q4*4+0..3 (l15 = row)
        #pragma unroll
        for (int mt = 0; mt < 2; ++mt) {
            float s = spart[mt];
            s += __shfl_xor(s, 16, 64);
            s += __shfl_xor(s, 32, 64);
            float w = __expf(s);           // scores ~ N(0,1/3): no max-subtraction needed
            Zacc[mt] += w;
            if (tid < 16) wAll[FI * MTILE + mt * 16 + l15] = w;   // wave0, q4==0 owns rows l15
            float w0 = __shfl(w, wb + 0, 64);
            float w1 = __shfl(w, wb + 1, 64);
            float w2 = __shfl(w, wb + 2, 64);
            float w3 = __shfl(w, wb + 3, 64);
            O[mt][0][0] += w0 * P[mt][0][0]; O[mt][0][1] += w1 * P[mt][0][1];
            O[mt][0][2] += w2 * P[mt][0][2]; O[mt][0][3] += w3 * P[mt][0][3];
            O[mt][1][0] += w0 * P[mt][1][0]; O[mt][1][1] += w1 * P[mt][1][1];
            O[mt][1][2] += w2 * P[mt][1][2]; O[mt][1][3] += w3 * P[mt][1][3];
        }
    }
}

__global__ __launch_bounds__(THREADS, 4)
void attn_main(Ptrs p, const unsigned short* WvB, const float* qk,
               float* outC, float* outA) {
    // qkS occupies the front of smem during the main loop; Ctmp reuses it after a barrier.
    __shared__ __align__(16) float smem[MTILE * 136];   // 17.4 KB
    __shared__ float wAll[NFEAT * MTILE];
    __shared__ float ZAll[MTILE];

    int tid  = threadIdx.x;
    int wave = tid >> 6;
    int lane = tid & 63;
    int l15  = lane & 15, q4 = lane >> 4;
    int row0 = blockIdx.x * MTILE;
    float* qkS = smem;

    float4 fA[8];
    s16x8  af[2][2], bf[2][2];
    f32x4  P[2][2], O[2][2];
    float  spart[2], Zacc[2];
    Zacc[0] = Zacc[1] = 0.f;
    #pragma unroll
    for (int mt = 0; mt < 2; ++mt) {
        O[mt][0] = f32x4{0.f, 0.f, 0.f, 0.f};
        O[mt][1] = f32x4{0.f, 0.f, 0.f, 0.f};
    }

    // prologue: first A-chunk in flight while qk is staged to LDS
    loadA<0, 0, 32>(p, row0, l15, q4, fA);
    for (int g = tid; g < 1664; g += THREADS) qkS[g] = qk[g];
    __syncthreads();

#define STEP(FI, CK0, DC, FIRST, LAST, NFI, NCK0, NDC)                          \
    loadB<FI, CK0, DC>(WvB, wave, l15, q4, bf);                                 \
    score_cvt<FI, CK0, DC, FIRST>(fA, qkS, q4, spart, af, P);                   \
    loadA<NFI, NCK0, NDC>(p, row0, l15, q4, fA);                                \
    __builtin_amdgcn_sched_barrier(0);                                          \
    mfma_tail<FI, DC, LAST>(af, bf, P, O, spart, Zacc, wAll, tid, lane, l15, q4);

#define STEPLAST(FI, CK0, DC, FIRST, LAST)                                      \
    loadB<FI, CK0, DC>(WvB, wave, l15, q4, bf);                                 \
    score_cvt<FI, CK0, DC, FIRST>(fA, qkS, q4, spart, af, P);                   \
    mfma_tail<FI, DC, LAST>(af, bf, P, O, spart, Zacc, wAll, tid, lane, l15, q4);

    // 27 chunks, barrier-free. Per step the vmem queue is [B(c) old, A(c+1) new]:
    // MFMA's B-wait never forces retirement of the A-prefetch.
    STEP(0,   0, 32, true,  true,   1,   0, 64)
    STEP(1,   0, 64, true,  true,   2,   0, 64)
    STEP(2,   0, 64, true,  false,  2,  64, 32)
    STEP(2,  64, 32, false, true,   3,   0, 64)
    STEP(3,   0, 64, true,  false,  3,  64, 64)
    STEP(3,  64, 64, false, true,   4,   0, 64)
    STEP(4,   0, 64, true,  false,  4,  64, 64)
    STEP(4,  64, 64, false, false,  4, 128, 64)
    STEP(4, 128, 64, false, true,   5,   0, 64)
    STEP(5,   0, 64, true,  false,  5,  64, 64)
    STEP(5,  64, 64, false, false,  5, 128, 64)
    STEP(5, 128, 64, false, false,  5, 192, 64)
    STEP(5, 192, 64, false, true,   6,   0, 64)
    STEP(6,   0, 64, true,  false,  6,  64, 64)
    STEP(6,  64, 64, false, false,  6, 128, 64)
    STEP(6, 128, 64, false, false,  6, 192, 64)
    STEP(6, 192, 64, false, false,  6, 256, 64)
    STEP(6, 256, 64, false, false,  6, 320, 64)
    STEP(6, 320, 64, false, true,   7,   0, 64)
    STEP(7,   0, 64, true,  false,  7,  64, 64)
    STEP(7,  64, 64, false, false,  7, 128, 64)
    STEP(7, 128, 64, false, false,  7, 192, 64)
    STEP(7, 192, 64, false, false,  7, 256, 64)
    STEP(7, 256, 64, false, false,  7, 320, 64)
    STEP(7, 320, 64, false, false,  7, 384, 64)
    STEP(7, 384, 64, false, false,  7, 448, 64)
    STEPLAST(7, 448, 64, false, true)
#undef STEP
#undef STEPLAST

    // publish Z (wave0, q4==0 lanes own rows l15 / 16+l15)
    if (tid < 16) { ZAll[tid] = Zacc[0]; ZAll[16 + tid] = Zacc[1]; }
    __syncthreads();                       // everyone done with qkS; wAll/ZAll visible

    // ---- epilogue: transpose O through LDS, coalesced float4 stores ----
    float* Ctmp = smem;                    // 32 x 136 fp32 = 17.4 KB
    #pragma unroll
    for (int mt = 0; mt < 2; ++mt) {
        #pragma unroll
        for (int rr = 0; rr < 4; ++rr) {
            int row = mt * 16 + q4 * 4 + rr;     // C/D layout: col = lane&15, row = quad*4 + reg
            float zi = 1.0f / ZAll[row];
            Ctmp[row * 136 + wave * 32 + l15]      = O[mt][0][rr] * zi;
            Ctmp[row * 136 + wave * 32 + 16 + l15] = O[mt][1][rr] * zi;
        }
    }
    __syncthreads();
    #pragma unroll
    for (int it = 0; it < 4; ++it) {
        int j = tid + it * THREADS;        // 0..1023 = 32 rows x 32 float4
        int r = j >> 5, c4 = (j & 31) * 4;
        *reinterpret_cast<float4*>(outC + (size_t)(row0 + r) * HID + c4) =
            *reinterpret_cast<const float4*>(Ctmp + r * 136 + c4);
    }
    if (tid < MTILE) {
        float zi = 1.0f / ZAll[tid];
        float4 a0, a1;
        a0.x = wAll[0 * MTILE + tid] * zi; a0.y = wAll[1 * MTILE + tid] * zi;
        a0.z = wAll[2 * MTILE + tid] * zi; a0.w = wAll[3 * MTILE + tid] * zi;
        a1.x = wAll[4 * MTILE + tid] * zi; a1.y = wAll[5 * MTILE + tid] * zi;
        a1.z = wAll[6 * MTILE + tid] * zi; a1.w = wAll[7 * MTILE + tid] * zi;
        float* dst = outA + (size_t)(row0 + tid) * NFEAT;
        *reinterpret_cast<float4*>(dst)     = a0;
        *reinterpret_cast<float4*>(dst + 4) = a1;
    }
}

extern "C" void kernel_launch(void* const* d_in, const int* in_sizes, int n_in,
                              void* d_out, int out_size, void* d_ws, size_t ws_size,
                              hipStream_t stream) {
    Ptrs p;
    // setup_inputs() dict order: feat0..feat7, then Wk0,Wv0,Wk1,Wv1,... (interleaved), then query
    for (int i = 0; i < NFEAT; ++i) {
        p.feat[i] = (const float*)d_in[i];
        p.wk[i]   = (const float*)d_in[NFEAT + 2 * i];
        p.wv[i]   = (const float*)d_in[NFEAT + 2 * i + 1];
    }
    p.q = (const float*)d_in[3 * NFEAT];

    // workspace layout: [WvB bf16: 128*1664*2 = 425984 B][qk fp32: 1664*4 B]
    unsigned short* WvB = (unsigned short*)d_ws;
    float* qk = (float*)((char*)d_ws + 128 * 1664 * 2);

    prep_all<<<NFEAT * 8 + NFEAT, 256, 0, stream>>>(p, WvB, qk);

    float* outC = (float*)d_out;
    float* outA = outC + (size_t)BATCH * HID;
    attn_main<<<BATCH / MTILE, THREADS, 0, stream>>>(p, WvB, qk, outC, outA);
}

// Round 4
// 287.457 us; speedup vs baseline: 3.0048x; 3.0048x over previous
//
#include <hip/hip_runtime.h>
#include <hip/hip_bf16.h>

#define THREADS 256
#define HID     128
#define BATCH   32768
#define NFEAT   8
#define NCH     52      // total 32-col chunks over all features

typedef __attribute__((ext_vector_type(4))) float f32x4;
typedef __attribute__((ext_vector_type(8))) short s16x8;

struct Ptrs {
    const float* feat[NFEAT];
    const float* wk[NFEAT];
    const float* wv[NFEAT];
    const float* q;
};

__device__ __forceinline__ unsigned short f2bf(float f) {
    union { __hip_bfloat16 h; unsigned short u; } c; c.h = __float2bfloat16(f); return c.u;
}

__device__ __forceinline__ s16x8 pack8(float4 x, float4 y) {
    s16x8 b;
    b[0] = (short)f2bf(x.x); b[1] = (short)f2bf(x.y);
    b[2] = (short)f2bf(x.z); b[3] = (short)f2bf(x.w);
    b[4] = (short)f2bf(y.x); b[5] = (short)f2bf(y.y);
    b[6] = (short)f2bf(y.z); b[7] = (short)f2bf(y.w);
    return b;
}

// runtime-indexed copies (prep kernel)
__device__ const int g_fdim[NFEAT] = {32, 64, 96, 128, 192, 256, 384, 512};
__device__ const int g_foff[NFEAT] = {0, 32, 96, 192, 320, 512, 768, 1152};
// compile-time copies
constexpr int c_fdim[NFEAT] = {32, 64, 96, 128, 192, 256, 384, 512};
constexpr int c_foff[NFEAT] = {0, 32, 96, 192, 320, 512, 768, 1152};

// chunk schedule: 52 chunks of 32 columns, covering features 0..7 in order
struct ChunkTab { int fi[NCH]; int ck[NCH]; };
constexpr ChunkTab make_tab() {
    ChunkTab t{};
    int c = 0;
    for (int f = 0; f < NFEAT; ++f)
        for (int k = 0; k < c_fdim[f]; k += 32) { t.fi[c] = f; t.ck[c] = k; ++c; }
    return t;
}
constexpr ChunkTab CT = make_tab();
static_assert(CT.fi[NCH - 1] == 7 && CT.ck[NCH - 1] == 480, "chunk table");

// ---------------- fused prep: Wv -> bf16 B-fragment layout, and qk = (Wk^T q)/sqrt(128) ----------------
__global__ void prep_all(Ptrs p, unsigned short* WvB, float* qk) {
    int bid = blockIdx.x;
    if (bid < NFEAT * 8) {
        int fi    = bid >> 3;
        int slice = bid & 7;
        int D  = g_fdim[fi];
        int Dg = D >> 3;
        const float* Wv = p.wv[fi];
        unsigned short* out = WvB + 128 * g_foff[fi];
        int h0  = slice * 16;
        int cnt = 16 * Dg;
        for (int e = threadIdx.x; e < cnt; e += blockDim.x) {
            int h  = h0 + e / Dg;
            int kg = e - (e / Dg) * Dg;
            const float* src = Wv + h * D + kg * 8;
            float4 x = *reinterpret_cast<const float4*>(src);
            float4 y = *reinterpret_cast<const float4*>(src + 4);
            *reinterpret_cast<s16x8*>(out + (kg * 128 + h) * 8) = pack8(x, y);
        }
    } else {
        int i = bid - NFEAT * 8;
        int d = g_fdim[i];
        const float* Wk = p.wk[i];
        const float* q  = p.q;
        for (int c = threadIdx.x; c < d; c += blockDim.x) {
            float s = 0.f;
            #pragma unroll 8
            for (int h = 0; h < HID; ++h) s = fmaf(q[h], Wk[h * d + c], s);
            qk[g_foff[i] + c] = s * 0.08838834764831845f;   // 1/sqrt(128)
        }
    }
}

// ---------------- main kernel: one wave owns 16 batch rows, full HID ----------------

// A chunk (16 rows x 32 cols) in MFMA fragment layout: lane(q4,l15) -> row l15, k = CK0+q4*8..+8
template<int FI, int CK0>
__device__ __forceinline__ void loadA1(const Ptrs& p, int rowg, int q4, float4 (&fa)[2]) {
    constexpr int D = c_fdim[FI];
    const float* b = p.feat[FI] + (size_t)rowg * D + CK0 + q4 * 8;
    fa[0] = *reinterpret_cast<const float4*>(b);
    fa[1] = *reinterpret_cast<const float4*>(b + 4);
}

// B chunk: 8 n-tiles (HID 128 = 8 x 16), k-group kg = CK0/8 + q4
template<int FI, int CK0>
__device__ __forceinline__ void loadB1(const unsigned short* WvB, int l15, int q4, s16x8 (&bb)[8]) {
    constexpr int FOFF = c_foff[FI];
    const unsigned short* Wb = WvB + 128 * FOFF + (size_t)(CK0 / 8 + q4) * 128 * 8 + l15 * 8;
    #pragma unroll
    for (int n = 0; n < 8; ++n)
        bb[n] = *reinterpret_cast<const s16x8*>(Wb + n * 16 * 8);
}

template<int C>
__device__ __forceinline__ void step(const Ptrs& p, const unsigned short* WvB, const float* qkS,
    int rowg, int l15, int q4,
    float4 (&fA)[3][2], s16x8 (&bf)[2][8],
    f32x4 (&P)[8], f32x4 (&O)[8], float& spart, float& Zacc, float (&wreg)[NFEAT])
{
    constexpr int FI   = CT.fi[C], CK0 = CT.ck[C];
    constexpr int D    = c_fdim[FI], FOFF = c_foff[FI];
    constexpr bool FIRST = (CK0 == 0), LAST = (CK0 + 32 == D);

    // prefetch B(c+1) then A(c+2): program order keeps bf(c) OLDER than these,
    // so the MFMA's counted vmcnt wait never drains the prefetch queue.
    if constexpr (C + 1 < NCH) loadB1<CT.fi[C + 1], CT.ck[C + 1]>(WvB, l15, q4, bf[(C + 1) & 1]);
    if constexpr (C + 2 < NCH) loadA1<CT.fi[C + 2], CT.ck[C + 2]>(p, rowg, q4, fA[(C + 2) % 3]);
    __builtin_amdgcn_sched_barrier(0);

    if constexpr (FIRST) {
        spart = 0.f;
        #pragma unroll
        for (int n = 0; n < 8; ++n) P[n] = f32x4{0.f, 0.f, 0.f, 0.f};
    }

    // score partial (fp32) + convert to bf16 A-fragment
    float4 x = fA[C % 3][0], y = fA[C % 3][1];
    float4 q0 = *reinterpret_cast<const float4*>(qkS + FOFF + CK0 + q4 * 8);
    float4 q1 = *reinterpret_cast<const float4*>(qkS + FOFF + CK0 + q4 * 8 + 4);
    spart += x.x * q0.x + x.y * q0.y + x.z * q0.z + x.w * q0.w
           + y.x * q1.x + y.y * q1.y + y.z * q1.z + y.w * q1.w;
    s16x8 af = pack8(x, y);

    #pragma unroll
    for (int n = 0; n < 8; ++n)
        P[n] = __builtin_amdgcn_mfma_f32_16x16x32_bf16(af, bf[C & 1][n], P[n], 0, 0, 0);

    if constexpr (LAST) {
        // spart covers k-slice q4*8.. of row l15; sum the 4 q4-groups -> full row score
        float s = spart;
        s += __shfl_xor(s, 16, 64);
        s += __shfl_xor(s, 32, 64);
        float w = __expf(s);              // scores ~ N(0,1/3): no max-subtraction needed
        Zacc += w;                        // every lane holds Z-partial for row l15
        wreg[FI] = w;
        // C/D layout: col = l15, row = q4*4+rr. Row r's w lives in lanes with l15==r.
        #pragma unroll
        for (int rr = 0; rr < 4; ++rr) {
            float wr = __shfl(w, (q4 << 4) + q4 * 4 + rr, 64);
            #pragma unroll
            for (int n = 0; n < 8; ++n) O[n][rr] += wr * P[n][rr];
        }
    }
}

template<int C>
__device__ __forceinline__ void run_steps(const Ptrs& p, const unsigned short* WvB, const float* qkS,
    int rowg, int l15, int q4,
    float4 (&fA)[3][2], s16x8 (&bf)[2][8],
    f32x4 (&P)[8], f32x4 (&O)[8], float& spart, float& Zacc, float (&wreg)[NFEAT])
{
    step<C>(p, WvB, qkS, rowg, l15, q4, fA, bf, P, O, spart, Zacc, wreg);
    if constexpr (C + 1 < NCH)
        run_steps<C + 1>(p, WvB, qkS, rowg, l15, q4, fA, bf, P, O, spart, Zacc, wreg);
}

__global__ __launch_bounds__(THREADS, 2)
void attn_main(Ptrs p, const unsigned short* WvB, const float* qk,
               float* outC, float* outA) {
    __shared__ __align__(16) float qkS[1664];   // 6.5 KB — only shared state

    int tid  = threadIdx.x;
    int wave = tid >> 6;
    int lane = tid & 63;
    int l15  = lane & 15, q4 = lane >> 4;
    int rowbase = blockIdx.x * 64 + wave * 16;  // this wave's 16 rows
    int rowg    = rowbase + l15;

    for (int g = tid; g < 1664; g += THREADS) qkS[g] = qk[g];
    __syncthreads();                            // last block-wide sync

    float4 fA[3][2];
    s16x8  bf[2][8];
    f32x4  P[8], O[8];
    float  spart = 0.f, Zacc = 0.f, wreg[NFEAT];
    #pragma unroll
    for (int n = 0; n < 8; ++n) O[n] = f32x4{0.f, 0.f, 0.f, 0.f};

    // prologue: A(0), A(1), B(0) in flight
    loadA1<0, 0>(p, rowg, q4, fA[0]);
    loadA1<1, 0>(p, rowg, q4, fA[1]);
    loadB1<0, 0>(WvB, l15, q4, bf[0]);

    run_steps<0>(p, WvB, qkS, rowg, l15, q4, fA, bf, P, O, spart, Zacc, wreg);

    // ---- wave-local epilogue ----
    float zi = 1.0f / Zacc;                     // every lane: 1/Z of row l15
    #pragma unroll
    for (int rr = 0; rr < 4; ++rr) {
        float zr = __shfl(zi, (q4 << 4) + q4 * 4 + rr, 64);
        int row = rowbase + q4 * 4 + rr;
        #pragma unroll
        for (int n = 0; n < 8; ++n)
            outC[(size_t)row * HID + n * 16 + l15] = O[n][rr] * zr;
    }
    if (q4 == 0) {                              // lanes 0..15 own rows l15
        float4 a0, a1;
        a0.x = wreg[0] * zi; a0.y = wreg[1] * zi; a0.z = wreg[2] * zi; a0.w = wreg[3] * zi;
        a1.x = wreg[4] * zi; a1.y = wreg[5] * zi; a1.z = wreg[6] * zi; a1.w = wreg[7] * zi;
        float* dst = outA + (size_t)rowg * NFEAT;
        *reinterpret_cast<float4*>(dst)     = a0;
        *reinterpret_cast<float4*>(dst + 4) = a1;
    }
}

extern "C" void kernel_launch(void* const* d_in, const int* in_sizes, int n_in,
                              void* d_out, int out_size, void* d_ws, size_t ws_size,
                              hipStream_t stream) {
    Ptrs p;
    // setup_inputs() dict order: feat0..feat7, then Wk0,Wv0,Wk1,Wv1,... (interleaved), then query
    for (int i = 0; i < NFEAT; ++i) {
        p.feat[i] = (const float*)d_in[i];
        p.wk[i]   = (const float*)d_in[NFEAT + 2 * i];
        p.wv[i]   = (const float*)d_in[NFEAT + 2 * i + 1];
    }
    p.q = (const float*)d_in[3 * NFEAT];

    // workspace layout: [WvB bf16: 128*1664*2 = 425984 B][qk fp32: 1664*4 B]
    unsigned short* WvB = (unsigned short*)d_ws;
    float* qk = (float*)((char*)d_ws + 128 * 1664 * 2);

    prep_all<<<NFEAT * 8 + NFEAT, 256, 0, stream>>>(p, WvB, qk);

    float* outC = (float*)d_out;
    float* outA = outC + (size_t)BATCH * HID;
    attn_main<<<BATCH / 64, THREADS, 0, stream>>>(p, WvB, qk, outC, outA);
}

// Round 5
// 279.827 us; speedup vs baseline: 3.0867x; 1.0273x over previous
//
#include <hip/hip_runtime.h>
#include <hip/hip_bf16.h>

#define THREADS 256
#define HID     128
#define BATCH   32768
#define NFEAT   8
#define NCH     52      // total 32-col chunks over all features

typedef __attribute__((ext_vector_type(4))) float f32x4;
typedef __attribute__((ext_vector_type(8))) short s16x8;

struct Ptrs {
    const float* feat[NFEAT];
    const float* wk[NFEAT];
    const float* wv[NFEAT];
    const float* q;
};

__device__ __forceinline__ unsigned short f2bf(float f) {
    union { __hip_bfloat16 h; unsigned short u; } c; c.h = __float2bfloat16(f); return c.u;
}

__device__ __forceinline__ s16x8 pack8(float4 x, float4 y) {
    s16x8 b;
    b[0] = (short)f2bf(x.x); b[1] = (short)f2bf(x.y);
    b[2] = (short)f2bf(x.z); b[3] = (short)f2bf(x.w);
    b[4] = (short)f2bf(y.x); b[5] = (short)f2bf(y.y);
    b[6] = (short)f2bf(y.z); b[7] = (short)f2bf(y.w);
    return b;
}

// async global->LDS, 16 B per lane: per-lane global src, wave-uniform LDS base
__device__ __forceinline__ void glds16(const unsigned short* g, unsigned short* l) {
    __builtin_amdgcn_global_load_lds(
        (const __attribute__((address_space(1))) unsigned int*)g,
        (__attribute__((address_space(3))) unsigned int*)l, 16, 0, 0);
}

// runtime-indexed copies (prep kernel)
__device__ const int g_fdim[NFEAT] = {32, 64, 96, 128, 192, 256, 384, 512};
__device__ const int g_foff[NFEAT] = {0, 32, 96, 192, 320, 512, 768, 1152};
// compile-time copies
constexpr int c_fdim[NFEAT] = {32, 64, 96, 128, 192, 256, 384, 512};
constexpr int c_foff[NFEAT] = {0, 32, 96, 192, 320, 512, 768, 1152};

// chunk schedule: 52 chunks of 32 columns, covering features 0..7 in order
struct ChunkTab { int fi[NCH]; int ck[NCH]; };
constexpr ChunkTab make_tab() {
    ChunkTab t{};
    int c = 0;
    for (int f = 0; f < NFEAT; ++f)
        for (int k = 0; k < c_fdim[f]; k += 32) { t.fi[c] = f; t.ck[c] = k; ++c; }
    return t;
}
constexpr ChunkTab CT = make_tab();
static_assert(CT.fi[NCH - 1] == 7 && CT.ck[NCH - 1] == 480, "chunk table");

// ---------------- fused prep: Wv -> bf16 B-fragment layout, and qk = (Wk^T q)/sqrt(128) ----------------
__global__ void prep_all(Ptrs p, unsigned short* WvB, float* qk) {
    int bid = blockIdx.x;
    if (bid < NFEAT * 8) {
        int fi    = bid >> 3;
        int slice = bid & 7;
        int D  = g_fdim[fi];
        int Dg = D >> 3;
        const float* Wv = p.wv[fi];
        unsigned short* out = WvB + 128 * g_foff[fi];
        int h0  = slice * 16;
        int cnt = 16 * Dg;
        for (int e = threadIdx.x; e < cnt; e += blockDim.x) {
            int h  = h0 + e / Dg;
            int kg = e - (e / Dg) * Dg;
            const float* src = Wv + h * D + kg * 8;
            float4 x = *reinterpret_cast<const float4*>(src);
            float4 y = *reinterpret_cast<const float4*>(src + 4);
            *reinterpret_cast<s16x8*>(out + (kg * 128 + h) * 8) = pack8(x, y);
        }
    } else {
        int i = bid - NFEAT * 8;
        int d = g_fdim[i];
        const float* Wk = p.wk[i];
        const float* q  = p.q;
        for (int c = threadIdx.x; c < d; c += blockDim.x) {
            float s = 0.f;
            #pragma unroll 8
            for (int h = 0; h < HID; ++h) s = fmaf(q[h], Wk[h * d + c], s);
            qk[g_foff[i] + c] = s * 0.08838834764831845f;   // 1/sqrt(128)
        }
    }
}

// ---------------- main kernel: wave owns 16 rows; B shared via LDS (gl_lds, 3-buffer) ----------------

// A chunk (16 rows x 32 cols) in MFMA fragment layout: lane(q4,l15) -> row l15, k = CK0+q4*8..+8
template<int FI, int CK0>
__device__ __forceinline__ void loadA1(const Ptrs& p, int rowg, int q4, float4 (&fa)[2]) {
    constexpr int D = c_fdim[FI];
    const float* b = p.feat[FI] + (size_t)rowg * D + CK0 + q4 * 8;
    fa[0] = *reinterpret_cast<const float4*>(b);
    fa[1] = *reinterpret_cast<const float4*>(b + 4);
}

// issue B chunk C -> LDS buffer (8 KB, wave-partitioned linear memcpy via global_load_lds)
template<int C>
__device__ __forceinline__ void issueB(const unsigned short* WvB, unsigned short* Bb,
                                       int wave, int lane) {
    constexpr int FI = CT.fi[C], CK0 = CT.ck[C];
    const unsigned short* gs = WvB + (size_t)(128 * c_foff[FI] + 128 * CK0) + wave * 1024 + lane * 8;
    unsigned short* ld = Bb + (C % 3) * 4096 + wave * 1024;
    glds16(gs, ld);
    glds16(gs + 512, ld + 512);
}

template<int C>
__device__ __forceinline__ void step(const Ptrs& p, const unsigned short* WvB,
    const float* qkS, unsigned short* Bb,
    int rowg, int lane, int l15, int q4, int wave,
    float4 (&fA)[3][2], f32x4 (&P)[8], f32x4 (&O)[8],
    float& spart, float& Zacc, float (&wreg)[NFEAT])
{
    constexpr int FI   = CT.fi[C], CK0 = CT.ck[C];
    constexpr int D    = c_fdim[FI], FOFF = c_foff[FI];
    constexpr bool FIRST = (CK0 == 0), LAST = (CK0 + 32 == D);

    // B(c) fragments from LDS: 16-lane groups read contiguous 256 B -> conflict-free
    const unsigned short* bb = Bb + (C % 3) * 4096 + (q4 * 128 + l15) * 8;
    s16x8 bf[8];
    #pragma unroll
    for (int n = 0; n < 8; ++n)
        bf[n] = *reinterpret_cast<const s16x8*>(bb + n * 128);
    __builtin_amdgcn_sched_barrier(0);

    // prefetch: glB(c+2) FIRST (so it is older than A(c+2) in the vmcnt queue), then A(c+2)
    if constexpr (C + 2 < NCH) {
        issueB<C + 2>(WvB, Bb, wave, lane);
        __builtin_amdgcn_sched_barrier(0);
        loadA1<CT.fi[C + 2], CT.ck[C + 2]>(p, rowg, q4, fA[(C + 2) % 3]);
    }
    __builtin_amdgcn_sched_barrier(0);

    if constexpr (FIRST) {
        spart = 0.f;
        #pragma unroll
        for (int n = 0; n < 8; ++n) P[n] = f32x4{0.f, 0.f, 0.f, 0.f};
    }

    // score partial (fp32) + convert to bf16 A-fragment
    float4 x = fA[C % 3][0], y = fA[C % 3][1];
    float4 q0 = *reinterpret_cast<const float4*>(qkS + FOFF + CK0 + q4 * 8);
    float4 q1 = *reinterpret_cast<const float4*>(qkS + FOFF + CK0 + q4 * 8 + 4);
    spart += x.x * q0.x + x.y * q0.y + x.z * q0.z + x.w * q0.w
           + y.x * q1.x + y.y * q1.y + y.z * q1.z + y.w * q1.w;
    s16x8 af = pack8(x, y);

    #pragma unroll
    for (int n = 0; n < 8; ++n)
        P[n] = __builtin_amdgcn_mfma_f32_16x16x32_bf16(af, bf[n], P[n], 0, 0, 0);

    if constexpr (LAST) {
        float s = spart;
        s += __shfl_xor(s, 16, 64);
        s += __shfl_xor(s, 32, 64);
        float w = __expf(s);              // scores ~ N(0,1/3): no max-subtraction needed
        Zacc += w;                        // every lane holds Z-partial for row l15
        wreg[FI] = w;
        // C/D layout: col = l15, row = q4*4+rr. Row r's w lives in lanes with l15==r.
        #pragma unroll
        for (int rr = 0; rr < 4; ++rr) {
            float wr = __shfl(w, (q4 << 4) + q4 * 4 + rr, 64);
            #pragma unroll
            for (int n = 0; n < 8; ++n) O[n][rr] += wr * P[n][rr];
        }
    }

    // non-draining barrier: wait only glB(c+1) (oldest); A(c+1), glB(c+2), A(c+2) stay in flight
    __builtin_amdgcn_sched_barrier(0);
    if constexpr (C + 1 < NCH) {
        constexpr int NW = (C + 2 < NCH) ? 6 : 2;
        asm volatile("s_waitcnt vmcnt(%0)" :: "i"(NW) : "memory");
        __builtin_amdgcn_sched_barrier(0);
        __builtin_amdgcn_s_barrier();
        __builtin_amdgcn_sched_barrier(0);
    }
}

template<int C>
__device__ __forceinline__ void run_steps(const Ptrs& p, const unsigned short* WvB,
    const float* qkS, unsigned short* Bb,
    int rowg, int lane, int l15, int q4, int wave,
    float4 (&fA)[3][2], f32x4 (&P)[8], f32x4 (&O)[8],
    float& spart, float& Zacc, float (&wreg)[NFEAT])
{
    step<C>(p, WvB, qkS, Bb, rowg, lane, l15, q4, wave, fA, P, O, spart, Zacc, wreg);
    if constexpr (C + 1 < NCH)
        run_steps<C + 1>(p, WvB, qkS, Bb, rowg, lane, l15, q4, wave, fA, P, O, spart, Zacc, wreg);
}

__global__ __launch_bounds__(THREADS, 2)
void attn_main(Ptrs p, const unsigned short* WvB, const float* qk,
               float* outC, float* outA) {
    __shared__ __align__(16) unsigned short Bb[3 * 4096];   // 24 KB: 3 x 8 KB B chunk buffers
    __shared__ __align__(16) float qkS[1664];               // 6.5 KB

    int tid  = threadIdx.x;
    int wave = tid >> 6;
    int lane = tid & 63;
    int l15  = lane & 15, q4 = lane >> 4;
    int rowbase = blockIdx.x * 64 + wave * 16;  // this wave's 16 rows
    int rowg    = rowbase + l15;

    float4 fA[3][2];
    f32x4  P[8], O[8];
    float  spart = 0.f, Zacc = 0.f, wreg[NFEAT];
    #pragma unroll
    for (int n = 0; n < 8; ++n) O[n] = f32x4{0.f, 0.f, 0.f, 0.f};

    // prologue: qk->LDS first (its vmem loads are OLDEST), then glB(0),glB(1), then A(0),A(1)
    for (int g = tid; g < 1664; g += THREADS) qkS[g] = qk[g];
    __builtin_amdgcn_sched_barrier(0);
    issueB<0>(WvB, Bb, wave, lane);
    issueB<1>(WvB, Bb, wave, lane);
    __builtin_amdgcn_sched_barrier(0);
    loadA1<0, 0>(p, rowg, q4, fA[0]);
    loadA1<CT.fi[1], CT.ck[1]>(p, rowg, q4, fA[1]);
    __builtin_amdgcn_sched_barrier(0);
    // qk loads + glB(0..1) drained (oldest); A(0),A(1) (4 youngest) stay in flight
    asm volatile("s_waitcnt vmcnt(4) lgkmcnt(0)" ::: "memory");
    __builtin_amdgcn_sched_barrier(0);
    __builtin_amdgcn_s_barrier();
    __builtin_amdgcn_sched_barrier(0);

    run_steps<0>(p, WvB, qkS, Bb, rowg, lane, l15, q4, wave, fA, P, O, spart, Zacc, wreg);

    // ---- wave-local epilogue ----
    float zi = 1.0f / Zacc;                     // every lane: 1/Z of row l15
    #pragma unroll
    for (int rr = 0; rr < 4; ++rr) {
        float zr = __shfl(zi, (q4 << 4) + q4 * 4 + rr, 64);
        int row = rowbase + q4 * 4 + rr;
        #pragma unroll
        for (int n = 0; n < 8; ++n)
            outC[(size_t)row * HID + n * 16 + l15] = O[n][rr] * zr;
    }
    if (q4 == 0) {                              // lanes 0..15 own rows l15
        float4 a0, a1;
        a0.x = wreg[0] * zi; a0.y = wreg[1] * zi; a0.z = wreg[2] * zi; a0.w = wreg[3] * zi;
        a1.x = wreg[4] * zi; a1.y = wreg[5] * zi; a1.z = wreg[6] * zi; a1.w = wreg[7] * zi;
        float* dst = outA + (size_t)rowg * NFEAT;
        *reinterpret_cast<float4*>(dst)     = a0;
        *reinterpret_cast<float4*>(dst + 4) = a1;
    }
}

extern "C" void kernel_launch(void* const* d_in, const int* in_sizes, int n_in,
                              void* d_out, int out_size, void* d_ws, size_t ws_size,
                              hipStream_t stream) {
    Ptrs p;
    // setup_inputs() dict order: feat0..feat7, then Wk0,Wv0,Wk1,Wv1,... (interleaved), then query
    for (int i = 0; i < NFEAT; ++i) {
        p.feat[i] = (const float*)d_in[i];
        p.wk[i]   = (const float*)d_in[NFEAT + 2 * i];
        p.wv[i]   = (const float*)d_in[NFEAT + 2 * i + 1];
    }
    p.q = (const float*)d_in[3 * NFEAT];

    // workspace layout: [WvB bf16: 128*1664*2 = 425984 B][qk fp32: 1664*4 B]
    unsigned short* WvB = (unsigned short*)d_ws;
    float* qk = (float*)((char*)d_ws + 128 * 1664 * 2);

    prep_all<<<NFEAT * 8 + NFEAT, 256, 0, stream>>>(p, WvB, qk);

    float* outC = (float*)d_out;
    float* outA = outC + (size_t)BATCH * HID;
    attn_main<<<BATCH / 64, THREADS, 0, stream>>>(p, WvB, qk, outC, outA);
}